// Round 9
// baseline (392.410 us; speedup 1.0000x reference)
//
#include <hip/hip_runtime.h>
#include <math.h>

typedef unsigned int u32;
typedef __attribute__((ext_vector_type(8))) short bf16x8;
typedef __attribute__((ext_vector_type(4))) float floatx4;

constexpr int NN = 100000;
constexpr int EE = 1600000;
constexpr int IND = 256;
constexpr int F1 = 32;
constexpr int HF = 128;   // H*F1
constexpr int C  = 40;
constexpr float SLOPE = 0.2f;

constexpr int CAP = 64;   // padded bucket capacity per dst (P(deg>=64)~1e-13 at lambda=16)
constexpr int H2ROW = 32; // u32 per h2b row: 20 bf16x2 + el2 word + pad -> 128B line-aligned

constexpr int G1_BLOCKS  = (NN + 127) / 128;     // 782 gemm1 blocks
constexpr int HB_BLOCKS  = (EE / 4 + 255) / 256; // 1563 edge-quad blocks (4 edges/thread)
constexpr int FAT_BLOCKS = G1_BLOCKS + HB_BLOCKS;

__device__ __forceinline__ float bf_lo(u32 v) { return __uint_as_float(v << 16); }
__device__ __forceinline__ float bf_hi(u32 v) { return __uint_as_float(v & 0xffff0000u); }

// hardware packed f32->bf16 (RNE), 1 inst instead of ~11; lo -> low half
__device__ __forceinline__ u32 pkbf(float lo, float hi) {
    u32 r;
    asm("v_cvt_pk_bf16_f32 %0, %1, %2" : "=v"(r) : "v"(lo), "v"(hi));
    return r;
}

// ================= hist (runs ALONE at the atomic-fabric floor) + W2 pack role =======
// blocks 0..HB_BLOCKS-1: 4 independent returning atomics/thread -> rank.
// block HB_BLOCKS: pack W2 (+ aux cols 40=W2@al2, 41=W2@ar2) into w2g.
__global__ __launch_bounds__(256) void k_hist(const int* __restrict__ dst,
                                              int* __restrict__ cnt,
                                              int* __restrict__ rank,
                                              const float* __restrict__ W2,
                                              const float* __restrict__ al2,
                                              const float* __restrict__ ar2,
                                              u32* __restrict__ w2g) {
    const int tid = threadIdx.x;
    if (blockIdx.x == HB_BLOCKS) {
        const int o = tid & 15;
        const int n0 = tid >> 4;
        for (int n = n0; n < 48; n += 16) {
            float f[8];
            #pragma unroll
            for (int j = 0; j < 8; ++j) {
                const int k = o * 8 + j;
                float v;
                if (n < C) v = W2[(size_t)k * C + n];
                else if (n == 40) {
                    v = 0.f;
                    for (int c = 0; c < C; ++c) v += W2[(size_t)k * C + c] * al2[c];
                } else if (n == 41) {
                    v = 0.f;
                    for (int c = 0; c < C; ++c) v += W2[(size_t)k * C + c] * ar2[c];
                } else v = 0.f;
                f[j] = v;
            }
            uint4 p;
            p.x = pkbf(f[0], f[1]);
            p.y = pkbf(f[2], f[3]);
            p.z = pkbf(f[4], f[5]);
            p.w = pkbf(f[6], f[7]);
            *(uint4*)&w2g[n * 64 + ((o ^ (n & 7)) << 2)] = p;
        }
        return;
    }
    const int e = (blockIdx.x * 256 + tid) * 4;
    if (e < EE) {   // EE % 4 == 0
        const int4 d4 = *(const int4*)&dst[e];
        int4 r4;
        r4.x = atomicAdd(&cnt[d4.x], 1);
        r4.y = atomicAdd(&cnt[d4.y], 1);
        r4.z = atomicAdd(&cnt[d4.z], 1);
        r4.w = atomicAdd(&cnt[d4.w], 1);
        *(int4*)&rank[e] = r4;
    }
}

// ============ FAT kernel: gemm1 blocks interleaved with bucket-scatter blocks ==========
// blockIdx%3==0 -> gemm1 (782 blocks, MFMA/LDS/HBM-read), else bscat (1563 blocks,
// pure scattered-store stream, atomic-free). Complementary pipes -> true overlap.
__global__ __launch_bounds__(256) void k_g1b(const float* __restrict__ feat,
                                             const float* __restrict__ W1,
                                             const float* __restrict__ al1,
                                             const float* __restrict__ ar1,
                                             u32* __restrict__ h1b,
                                             float* __restrict__ el1,
                                             float* __restrict__ er1,
                                             const int* __restrict__ src,
                                             const int* __restrict__ dst,
                                             const int* __restrict__ rank,
                                             int* __restrict__ colp) {
    __shared__ u32 w1t[128 * 64];   // 32KB: one K-half of W1^T packed bf16
    const int bx = blockIdx.x;
    const int tid = threadIdx.x;

    if (bx % 3 != 0) {
        // ---------------- bucket-scatter role ----------------
        const int hb = bx - bx / 3 - 1;
        const int e = (hb * 256 + tid) * 4;
        if (e < EE) {   // EE % 4 == 0
            const int4 d4 = *(const int4*)&dst[e];
            const int4 s4 = *(const int4*)&src[e];
            const int4 r4 = *(const int4*)&rank[e];
            colp[(d4.x << 6) + r4.x] = s4.x;
            colp[(d4.y << 6) + r4.y] = s4.y;
            colp[(d4.z << 6) + r4.z] = s4.z;
            colp[(d4.w << 6) + r4.w] = s4.w;
        }
        return;
    }

    // ---------------- gemm1 role ----------------
    const int bid = bx / 3;
    const int w = tid >> 6, lane = tid & 63;
    const int quad = lane >> 4, l15 = lane & 15;
    const int rbase = bid * 128 + w * 32;

    float alv[4][2], arv[4][2];
    #pragma unroll
    for (int h = 0; h < 4; ++h) {
        alv[h][0] = al1[h * F1 + l15];
        alv[h][1] = al1[h * F1 + 16 + l15];
        arv[h][0] = ar1[h * F1 + l15];
        arv[h][1] = ar1[h * F1 + 16 + l15];
    }

    floatx4 acc[2][8] = {};
    for (int pass = 0; pass < 2; ++pass) {
        // stage one K-half (octets pass*16 .. pass*16+15)
        {
            const int n = tid & 127;
            const int o0 = (tid >> 7) * 8;
            for (int i = 0; i < 8; ++i) {
                const int o = o0 + i;            // in-pass octet 0..15
                const int ko = pass * 16 + o;    // global octet
                float f0 = W1[(size_t)(ko * 8 + 0) * HF + n];
                float f1 = W1[(size_t)(ko * 8 + 1) * HF + n];
                float f2 = W1[(size_t)(ko * 8 + 2) * HF + n];
                float f3 = W1[(size_t)(ko * 8 + 3) * HF + n];
                float f4 = W1[(size_t)(ko * 8 + 4) * HF + n];
                float f5 = W1[(size_t)(ko * 8 + 5) * HF + n];
                float f6 = W1[(size_t)(ko * 8 + 6) * HF + n];
                float f7 = W1[(size_t)(ko * 8 + 7) * HF + n];
                uint4 p;
                p.x = pkbf(f0, f1);
                p.y = pkbf(f2, f3);
                p.z = pkbf(f4, f5);
                p.w = pkbf(f6, f7);
                *(uint4*)&w1t[n * 64 + ((o ^ (n & 7)) << 2)] = p;
            }
        }
        __syncthreads();
        for (int ks = 0; ks < 4; ++ks) {
            const int gk = pass * 4 + ks;   // global k-step
            bf16x8 a[2];
            #pragma unroll
            for (int ri = 0; ri < 2; ++ri) {
                int row = rbase + ri * 16 + l15;
                row = row < NN ? row : NN - 1;
                const size_t base = (size_t)row * IND + gk * 32 + quad * 8;
                const float4 f0 = *(const float4*)&feat[base];
                const float4 f1 = *(const float4*)&feat[base + 4];
                uint4 p;
                p.x = pkbf(f0.x, f0.y);
                p.y = pkbf(f0.z, f0.w);
                p.z = pkbf(f1.x, f1.y);
                p.w = pkbf(f1.z, f1.w);
                a[ri] = *(bf16x8*)&p;
            }
            const int g = ks * 4 + quad;    // in-pass octet
            #pragma unroll
            for (int ci = 0; ci < 8; ++ci) {
                const int n = ci * 16 + l15;
                uint4 bw = *(const uint4*)&w1t[n * 64 + ((g ^ (n & 7)) << 2)];
                bf16x8 b = *(bf16x8*)&bw;
                acc[0][ci] = __builtin_amdgcn_mfma_f32_16x16x32_bf16(a[0], b, acc[0][ci], 0, 0, 0);
                acc[1][ci] = __builtin_amdgcn_mfma_f32_16x16x32_bf16(a[1], b, acc[1][ci], 0, 0, 0);
            }
        }
        __syncthreads();
    }

    #pragma unroll
    for (int ri = 0; ri < 2; ++ri) {
        #pragma unroll
        for (int r = 0; r < 4; ++r) {
            const int row = rbase + ri * 16 + quad * 4 + r;
            const bool rok = row < NN;
            #pragma unroll
            for (int h = 0; h < 4; ++h) {
                float pe = acc[ri][2 * h][r] * alv[h][0] + acc[ri][2 * h + 1][r] * alv[h][1];
                float pr = acc[ri][2 * h][r] * arv[h][0] + acc[ri][2 * h + 1][r] * arv[h][1];
                #pragma unroll
                for (int m = 1; m < 16; m <<= 1) {
                    pe += __shfl_xor(pe, m, 64);
                    pr += __shfl_xor(pr, m, 64);
                }
                if (l15 == 0 && rok) {
                    el1[row * 4 + h] = pe;
                    er1[row * 4 + h] = pr;
                }
            }
            #pragma unroll
            for (int ci = 0; ci < 8; ++ci) {
                float v = acc[ri][ci][r];
                float vn = __shfl_xor(v, 1, 64);
                if (!(lane & 1) && rok) {
                    h1b[(size_t)row * 64 + ci * 8 + (l15 >> 1)] = pkbf(v, vn);
                }
            }
        }
    }
}

// ========== fused layer-1 aggregation + GEMM2: 16 dsts/block == one 16-row tile ======
// Phase 1 (agg): 16-lane group per dst, 4-deep edge ILP, ELU -> bf16 row into LDS xt.
// Phase 2 (gemm2): waves 0..2 each compute one 16-col slab of x @ [W2|aux] (4 MFMAs)
// and write h2b (separate buffer from h1b -> no aliasing race) + el2/er2.
__global__ __launch_bounds__(256) void k_agg1f(const int* __restrict__ cnt,
                                               const int* __restrict__ colp,
                                               const u32* __restrict__ h1b,
                                               const float* __restrict__ el1,
                                               const float* __restrict__ er1,
                                               const float* __restrict__ b1,
                                               const u32* __restrict__ w2g,
                                               u32* __restrict__ h2b,
                                               float* __restrict__ er2) {
    __shared__ u32 xt[16][68];   // 16 rows x 64 u32 (+4 pad: 2-way max bank aliasing)
    const int lane = threadIdx.x & 63, wid = threadIdx.x >> 6;
    const int g = lane >> 4, li = lane & 15;
    const int d = blockIdx.x * 16 + wid * 4 + g;      // grid sized exactly: d < NN
    const int head = li >> 2;
    const float erd = er1[d * 4 + head];
    const int beg = d << 6;
    const int end = beg + cnt[d];
    const u32 li16 = (u32)li << 4;
    const u32 hoff = (u32)head << 2;

    float a0 = 0.f, a1 = 0.f, a2 = 0.f, a3 = 0.f;
    float a4 = 0.f, a5 = 0.f, a6 = 0.f, a7 = 0.f;
    float ssum = 0.f;

    auto body = [&](int e) {
        const bool act = e < end;
        int s = colp[act ? e : beg];   // bucket slots always in-bounds of colp
        s = act ? s : 0;               // pad slots may be uninitialized
        const u32 rb = (u32)s << 8;
        const uint4 v = *(const uint4*)((const char*)h1b + (rb + li16));
        float c = *(const float*)((const char*)el1 + (((u32)s << 4) + hoff)) + erd;
        c = fmaxf(c, SLOPE * c);
        float w = __expf(c);
        w = act ? w : 0.f;
        ssum += w;
        a0 += w * bf_lo(v.x); a1 += w * bf_hi(v.x);
        a2 += w * bf_lo(v.y); a3 += w * bf_hi(v.y);
        a4 += w * bf_lo(v.z); a5 += w * bf_hi(v.z);
        a6 += w * bf_lo(v.w); a7 += w * bf_hi(v.w);
    };

    int e = beg;
    while (__any(e < end)) {
        body(e);
        body(e + 1);
        body(e + 2);
        body(e + 3);
        e += 4;
    }

    const float inv = ssum > 0.f ? 1.f / ssum : 0.f;
    const float4 ba = *(const float4*)&b1[8 * li];
    const float4 bb = *(const float4*)&b1[8 * li + 4];
    float r0 = a0 * inv + ba.x, r1 = a1 * inv + ba.y;
    float r2 = a2 * inv + ba.z, r3 = a3 * inv + ba.w;
    float r4 = a4 * inv + bb.x, r5 = a5 * inv + bb.y;
    float r6 = a6 * inv + bb.z, r7 = a7 * inv + bb.w;
    r0 = r0 > 0.f ? r0 : __expf(r0) - 1.f;
    r1 = r1 > 0.f ? r1 : __expf(r1) - 1.f;
    r2 = r2 > 0.f ? r2 : __expf(r2) - 1.f;
    r3 = r3 > 0.f ? r3 : __expf(r3) - 1.f;
    r4 = r4 > 0.f ? r4 : __expf(r4) - 1.f;
    r5 = r5 > 0.f ? r5 : __expf(r5) - 1.f;
    r6 = r6 > 0.f ? r6 : __expf(r6) - 1.f;
    r7 = r7 > 0.f ? r7 : __expf(r7) - 1.f;
    uint4 p;
    p.x = pkbf(r0, r1);
    p.y = pkbf(r2, r3);
    p.z = pkbf(r4, r5);
    p.w = pkbf(r6, r7);
    *(uint4*)&xt[wid * 4 + g][4 * li] = p;
    __syncthreads();

    // ---- gemm2 phase: wave wid (<3) computes cols [wid*16, wid*16+16) ----
    if (wid < 3) {
        const int ci = wid;
        const int quad = g;               // lane>>4
        const int n = ci * 16 + li;
        floatx4 acc = {};
        #pragma unroll
        for (int ks = 0; ks < 4; ++ks) {
            const uint4 ax = *(const uint4*)&xt[li][ks * 16 + quad * 4];
            const bf16x8 a = *(const bf16x8*)&ax;
            const int gg = ks * 4 + quad;
            const uint4 bw = *(const uint4*)&w2g[n * 64 + ((gg ^ (n & 7)) << 2)];
            const bf16x8 b = *(const bf16x8*)&bw;
            acc = __builtin_amdgcn_mfma_f32_16x16x32_bf16(a, b, acc, 0, 0, 0);
        }
        #pragma unroll
        for (int r = 0; r < 4; ++r) {
            const int row = blockIdx.x * 16 + quad * 4 + r;
            const float v = acc[r];
            const float vn = __shfl_xor(v, 1, 64);
            if (ci < 2) {
                if (!(lane & 1))
                    h2b[(size_t)row * H2ROW + ci * 8 + (li >> 1)] = pkbf(v, vn);
            } else {
                if (!(lane & 1) && li < 8)
                    h2b[(size_t)row * H2ROW + 16 + (li >> 1)] = pkbf(v, vn);
                else if (li == 8)
                    h2b[(size_t)row * H2ROW + 20] = __float_as_uint(v);
                else if (li == 9)
                    er2[row] = v;
            }
        }
    }
}

// ================= layer-2 aggregation: 16-lane group per dst, 4-deep edge ILP =======
__global__ __launch_bounds__(256) void k_agg2(const int* __restrict__ cnt,
                                              const int* __restrict__ colp,
                                              const u32* __restrict__ h2b,
                                              const float* __restrict__ er2,
                                              const float* __restrict__ b2,
                                              float* __restrict__ out) {
    const int lane = threadIdx.x & 63, wid = threadIdx.x >> 6;
    const int g = lane >> 4, li = lane & 15;
    const int d = blockIdx.x * 16 + wid * 4 + g;      // grid sized exactly: d < NN
    const float erd = er2[d];
    const int beg = d << 6;
    const int end = beg + cnt[d];
    const u32 ob = (u32)(li < 12 ? 2 * li : 22) << 2;  // byte offset within 128B row

    float a0 = 0.f, a1 = 0.f, a2 = 0.f, a3 = 0.f;
    float ssum = 0.f;

    auto body = [&](int e) {
        const bool act = e < end;
        int s = colp[act ? e : beg];
        s = act ? s : 0;
        const u32 rb = (u32)s << 7;                      // s*128 bytes
        const uint2 v = *(const uint2*)((const char*)h2b + (rb + ob));
        float c = *(const float*)((const char*)h2b + rb + 80) + erd;
        c = fmaxf(c, SLOPE * c);
        float w = __expf(c);
        w = act ? w : 0.f;
        ssum += w;
        a0 += w * bf_lo(v.x); a1 += w * bf_hi(v.x);
        a2 += w * bf_lo(v.y); a3 += w * bf_hi(v.y);
    };

    int e = beg;
    while (__any(e < end)) {
        body(e);
        body(e + 1);
        body(e + 2);
        body(e + 3);
        e += 4;
    }

    if (li < 10) {
        const float inv = ssum > 0.f ? 1.f / ssum : 0.f;
        const float4 b = *(const float4*)&b2[4 * li];
        float4 r;
        r.x = a0 * inv + b.x;
        r.y = a1 * inv + b.y;
        r.z = a2 * inv + b.z;
        r.w = a3 * inv + b.w;
        *(float4*)&out[(size_t)d * C + 4 * li] = r;
    }
}

extern "C" void kernel_launch(void* const* d_in, const int* in_sizes, int n_in,
                              void* d_out, int out_size, void* d_ws, size_t ws_size,
                              hipStream_t stream) {
    const float* feat = (const float*)d_in[0];
    const int*   src  = (const int*)d_in[1];
    const int*   dst  = (const int*)d_in[2];
    const float* W1   = (const float*)d_in[3];
    const float* al1  = (const float*)d_in[4];
    const float* ar1  = (const float*)d_in[5];
    const float* b1   = (const float*)d_in[6];
    const float* W2   = (const float*)d_in[7];
    const float* al2  = (const float*)d_in[8];
    const float* ar2  = (const float*)d_in[9];
    const float* b2   = (const float*)d_in[10];
    float* out = (float*)d_out;

    // ---- workspace layout ----
    u32*   h1b = (u32*)d_ws;                        // N*64 u32 (bf16 h1 rows)
    u32*   xb2 = h1b + (size_t)NN * 64;             // N*64 u32: rank, then h2b (N*32)
    float* el1 = (float*)(xb2 + (size_t)NN * 64);   // N*4
    float* er1 = el1 + (size_t)NN * 4;              // N*4
    int* cnt   = (int*)(er1 + (size_t)NN * 4);      // N
    int* colp  = cnt + NN;                          // N*CAP padded buckets
    float* er2 = (float*)(colp + (size_t)NN * CAP); // N
    u32*   w2g = (u32*)(er2 + NN);                  // 48*64 u32 packed W2 tile
    int* rank  = (int*)xb2;                         // E ints, dead before agg1f writes h2b
    u32*   h2b = xb2;

    // ---- hist alone (atomic fabric owns the machine) + W2 pack role ----
    hipMemsetAsync(cnt, 0, (size_t)NN * sizeof(int), stream);
    k_hist<<<HB_BLOCKS + 1, 256, 0, stream>>>(dst, cnt, rank, W2, al2, ar2, w2g);

    // ---- GEMM1 overlapped with bucket scatter (complementary pipes) ----
    k_g1b<<<FAT_BLOCKS, 256, 0, stream>>>(feat, W1, al1, ar1, h1b, el1, er1,
                                          src, dst, rank, colp);

    // ---- layer 1 aggregation fused with GEMM2 ----
    k_agg1f<<<NN / 16, 256, 0, stream>>>(cnt, colp, h1b, el1, er1, b1,
                                         w2g, h2b, er2);

    // ---- layer 2 aggregation ----
    k_agg2<<<NN / 16, 256, 0, stream>>>(cnt, colp, h2b, er2, b2, out);
}

// Round 10
// 391.837 us; speedup vs baseline: 1.0015x; 1.0015x over previous
//
#include <hip/hip_runtime.h>
#include <math.h>

typedef unsigned int u32;
typedef __attribute__((ext_vector_type(8))) short bf16x8;
typedef __attribute__((ext_vector_type(4))) float floatx4;

constexpr int NN = 100000;
constexpr int EE = 1600000;
constexpr int IND = 256;
constexpr int F1 = 32;
constexpr int HF = 128;   // H*F1
constexpr int C  = 40;
constexpr float SLOPE = 0.2f;

constexpr int CAP = 64;   // padded bucket capacity per dst (P(deg>=64)~1e-13 at lambda=16)
constexpr int H2ROW = 32; // u32 per h2b row: 20 bf16x2 + el2 word + pad -> 128B line-aligned

constexpr int G1_BLOCKS  = (NN + 127) / 128;     // 782 gemm1 blocks
constexpr int HB_BLOCKS  = (EE / 4 + 255) / 256; // 1563 edge-quad blocks (4 edges/thread)
constexpr int FAT_BLOCKS = G1_BLOCKS + HB_BLOCKS;

__device__ __forceinline__ float bf_lo(u32 v) { return __uint_as_float(v << 16); }
__device__ __forceinline__ float bf_hi(u32 v) { return __uint_as_float(v & 0xffff0000u); }

// hardware packed f32->bf16 (RNE), 1 inst instead of ~11; lo -> low half
__device__ __forceinline__ u32 pkbf(float lo, float hi) {
    u32 r;
    asm("v_cvt_pk_bf16_f32 %0, %1, %2" : "=v"(r) : "v"(lo), "v"(hi));
    return r;
}

// ============ FAT kernel: gemm1 blocks interleaved with hist blocks (best pairing) =====
// blockIdx%3==0 -> gemm1 (782 blocks, 64KB W1 stage — measured faster than 32KB 2-pass),
// else hist (1563 blocks, 4 independent returning atomics/thread -> rank).
__global__ __launch_bounds__(256) void k_g1h(const float* __restrict__ feat,
                                             const float* __restrict__ W1,
                                             const float* __restrict__ al1,
                                             const float* __restrict__ ar1,
                                             u32* __restrict__ h1b,
                                             float* __restrict__ el1,
                                             float* __restrict__ er1,
                                             const int* __restrict__ dst,
                                             int* __restrict__ cnt,
                                             int* __restrict__ rank) {
    __shared__ u32 w1t[128 * 128];
    const int bx = blockIdx.x;
    const int tid = threadIdx.x;

    if (bx % 3 != 0) {
        // ---------------- hist role ----------------
        const int hb = bx - bx / 3 - 1;
        const int e = (hb * 256 + tid) * 4;
        if (e < EE) {   // EE % 4 == 0
            const int4 d4 = *(const int4*)&dst[e];
            int4 r4;
            r4.x = atomicAdd(&cnt[d4.x], 1);
            r4.y = atomicAdd(&cnt[d4.y], 1);
            r4.z = atomicAdd(&cnt[d4.z], 1);
            r4.w = atomicAdd(&cnt[d4.w], 1);
            *(int4*)&rank[e] = r4;
        }
        return;
    }

    // ---------------- gemm1 role ----------------
    const int bid = bx / 3;
    {
        const int n = tid & 127;
        const int o0 = (tid >> 7) * 16;
        for (int i = 0; i < 16; ++i) {
            const int o = o0 + i;
            float f0 = W1[(size_t)(o * 8 + 0) * HF + n];
            float f1 = W1[(size_t)(o * 8 + 1) * HF + n];
            float f2 = W1[(size_t)(o * 8 + 2) * HF + n];
            float f3 = W1[(size_t)(o * 8 + 3) * HF + n];
            float f4 = W1[(size_t)(o * 8 + 4) * HF + n];
            float f5 = W1[(size_t)(o * 8 + 5) * HF + n];
            float f6 = W1[(size_t)(o * 8 + 6) * HF + n];
            float f7 = W1[(size_t)(o * 8 + 7) * HF + n];
            uint4 p;
            p.x = pkbf(f0, f1);
            p.y = pkbf(f2, f3);
            p.z = pkbf(f4, f5);
            p.w = pkbf(f6, f7);
            *(uint4*)&w1t[n * 128 + ((o ^ (n & 7)) << 2)] = p;
        }
    }
    __syncthreads();

    const int w = tid >> 6, lane = tid & 63;
    const int quad = lane >> 4, l15 = lane & 15;
    const int rbase = bid * 128 + w * 32;

    float alv[4][2], arv[4][2];
    #pragma unroll
    for (int h = 0; h < 4; ++h) {
        alv[h][0] = al1[h * F1 + l15];
        alv[h][1] = al1[h * F1 + 16 + l15];
        arv[h][0] = ar1[h * F1 + l15];
        arv[h][1] = ar1[h * F1 + 16 + l15];
    }

    floatx4 acc[2][8] = {};
    for (int ks = 0; ks < 8; ++ks) {
        bf16x8 a[2];
        #pragma unroll
        for (int ri = 0; ri < 2; ++ri) {
            int row = rbase + ri * 16 + l15;
            row = row < NN ? row : NN - 1;
            const size_t base = (size_t)row * IND + ks * 32 + quad * 8;
            const float4 f0 = *(const float4*)&feat[base];
            const float4 f1 = *(const float4*)&feat[base + 4];
            uint4 p;
            p.x = pkbf(f0.x, f0.y);
            p.y = pkbf(f0.z, f0.w);
            p.z = pkbf(f1.x, f1.y);
            p.w = pkbf(f1.z, f1.w);
            a[ri] = *(bf16x8*)&p;
        }
        const int g = ks * 4 + quad;
        #pragma unroll
        for (int ci = 0; ci < 8; ++ci) {
            const int n = ci * 16 + l15;
            uint4 bw = *(const uint4*)&w1t[n * 128 + ((g ^ (n & 7)) << 2)];
            bf16x8 b = *(bf16x8*)&bw;
            acc[0][ci] = __builtin_amdgcn_mfma_f32_16x16x32_bf16(a[0], b, acc[0][ci], 0, 0, 0);
            acc[1][ci] = __builtin_amdgcn_mfma_f32_16x16x32_bf16(a[1], b, acc[1][ci], 0, 0, 0);
        }
    }

    #pragma unroll
    for (int ri = 0; ri < 2; ++ri) {
        #pragma unroll
        for (int r = 0; r < 4; ++r) {
            const int row = rbase + ri * 16 + quad * 4 + r;
            const bool rok = row < NN;
            #pragma unroll
            for (int h = 0; h < 4; ++h) {
                float pe = acc[ri][2 * h][r] * alv[h][0] + acc[ri][2 * h + 1][r] * alv[h][1];
                float pr = acc[ri][2 * h][r] * arv[h][0] + acc[ri][2 * h + 1][r] * arv[h][1];
                #pragma unroll
                for (int m = 1; m < 16; m <<= 1) {
                    pe += __shfl_xor(pe, m, 64);
                    pr += __shfl_xor(pr, m, 64);
                }
                if (l15 == 0 && rok) {
                    el1[row * 4 + h] = pe;
                    er1[row * 4 + h] = pr;
                }
            }
            #pragma unroll
            for (int ci = 0; ci < 8; ++ci) {
                float v = acc[ri][ci][r];
                float vn = __shfl_xor(v, 1, 64);
                if (!(lane & 1) && rok) {
                    h1b[(size_t)row * 64 + ci * 8 + (l15 >> 1)] = pkbf(v, vn);
                }
            }
        }
    }
}

// ============ bucket scatter + W2 pack role ==========
// blocks 0..HB_BLOCKS-1: atomic-free scatter p=(dst<<6)+rank, 4 edges/thread.
// block HB_BLOCKS: pack W2 (+ aux cols 40=W2@al2, 41=W2@ar2) into w2g.
__global__ __launch_bounds__(256) void k_bscat(const int* __restrict__ src,
                                               const int* __restrict__ dst,
                                               const int* __restrict__ rank,
                                               int* __restrict__ colp,
                                               const float* __restrict__ W2,
                                               const float* __restrict__ al2,
                                               const float* __restrict__ ar2,
                                               u32* __restrict__ w2g) {
    const int tid = threadIdx.x;
    if (blockIdx.x == HB_BLOCKS) {
        const int o = tid & 15;
        const int n0 = tid >> 4;
        for (int n = n0; n < 48; n += 16) {
            float f[8];
            #pragma unroll
            for (int j = 0; j < 8; ++j) {
                const int k = o * 8 + j;
                float v;
                if (n < C) v = W2[(size_t)k * C + n];
                else if (n == 40) {
                    v = 0.f;
                    for (int c = 0; c < C; ++c) v += W2[(size_t)k * C + c] * al2[c];
                } else if (n == 41) {
                    v = 0.f;
                    for (int c = 0; c < C; ++c) v += W2[(size_t)k * C + c] * ar2[c];
                } else v = 0.f;
                f[j] = v;
            }
            uint4 p;
            p.x = pkbf(f[0], f[1]);
            p.y = pkbf(f[2], f[3]);
            p.z = pkbf(f[4], f[5]);
            p.w = pkbf(f[6], f[7]);
            *(uint4*)&w2g[n * 64 + ((o ^ (n & 7)) << 2)] = p;
        }
        return;
    }
    const int e = (blockIdx.x * 256 + tid) * 4;
    if (e < EE) {   // EE % 4 == 0
        const int4 d4 = *(const int4*)&dst[e];
        const int4 s4 = *(const int4*)&src[e];
        const int4 r4 = *(const int4*)&rank[e];
        colp[(d4.x << 6) + r4.x] = s4.x;
        colp[(d4.y << 6) + r4.y] = s4.y;
        colp[(d4.z << 6) + r4.z] = s4.z;
        colp[(d4.w << 6) + r4.w] = s4.w;
    }
}

// ========== fused layer-1 aggregation + GEMM2: 16 dsts/block == one 16-row tile ======
// Phase 1 (agg): 16-lane group per dst, 4-deep edge ILP, colp prefetched one quad
// ahead (breaks the colp->row dependent-load chain), ELU -> bf16 row into LDS xt.
// Phase 2 (gemm2): waves 0..2 each compute one 16-col slab of x @ [W2|aux] (4 MFMAs).
__global__ __launch_bounds__(256) void k_agg1f(const int* __restrict__ cnt,
                                               const int* __restrict__ colp,
                                               const u32* __restrict__ h1b,
                                               const float* __restrict__ el1,
                                               const float* __restrict__ er1,
                                               const float* __restrict__ b1,
                                               const u32* __restrict__ w2g,
                                               u32* __restrict__ h2b,
                                               float* __restrict__ er2) {
    __shared__ u32 xt[16][68];   // 16 rows x 64 u32 (+4 pad: 2-way max bank aliasing)
    const int lane = threadIdx.x & 63, wid = threadIdx.x >> 6;
    const int g = lane >> 4, li = lane & 15;
    const int d = blockIdx.x * 16 + wid * 4 + g;      // grid sized exactly: d < NN
    const int head = li >> 2;
    const float erd = er1[d * 4 + head];
    const int beg = d << 6;
    const int end = beg + cnt[d];
    const u32 li16 = (u32)li << 4;
    const u32 hoff = (u32)head << 2;

    float a0 = 0.f, a1 = 0.f, a2 = 0.f, a3 = 0.f;
    float a4 = 0.f, a5 = 0.f, a6 = 0.f, a7 = 0.f;
    float ssum = 0.f;

    // clamped colp read: in-bounds always; 0 for inactive slots (pad garbage discarded)
    auto pres = [&](int e) -> int {
        const bool act = e < end;
        const int s = colp[act ? e : beg];
        return act ? s : 0;
    };

    auto bodyS = [&](int s, int e) {
        const bool act = e < end;
        const u32 rb = (u32)s << 8;
        const uint4 v = *(const uint4*)((const char*)h1b + (rb + li16));
        float c = *(const float*)((const char*)el1 + (((u32)s << 4) + hoff)) + erd;
        c = fmaxf(c, SLOPE * c);
        float w = __expf(c);
        w = act ? w : 0.f;
        ssum += w;
        a0 += w * bf_lo(v.x); a1 += w * bf_hi(v.x);
        a2 += w * bf_lo(v.y); a3 += w * bf_hi(v.y);
        a4 += w * bf_lo(v.z); a5 += w * bf_hi(v.z);
        a6 += w * bf_lo(v.w); a7 += w * bf_hi(v.w);
    };

    int e = beg;
    int4 cur;
    cur.x = pres(e);
    cur.y = pres(e + 1);
    cur.z = pres(e + 2);
    cur.w = pres(e + 3);
    while (__any(e < end)) {
        int4 nxt;
        nxt.x = pres(e + 4);
        nxt.y = pres(e + 5);
        nxt.z = pres(e + 6);
        nxt.w = pres(e + 7);
        bodyS(cur.x, e);
        bodyS(cur.y, e + 1);
        bodyS(cur.z, e + 2);
        bodyS(cur.w, e + 3);
        cur = nxt;
        e += 4;
    }

    const float inv = ssum > 0.f ? 1.f / ssum : 0.f;
    const float4 ba = *(const float4*)&b1[8 * li];
    const float4 bb = *(const float4*)&b1[8 * li + 4];
    float r0 = a0 * inv + ba.x, r1 = a1 * inv + ba.y;
    float r2 = a2 * inv + ba.z, r3 = a3 * inv + ba.w;
    float r4 = a4 * inv + bb.x, r5 = a5 * inv + bb.y;
    float r6 = a6 * inv + bb.z, r7 = a7 * inv + bb.w;
    r0 = r0 > 0.f ? r0 : __expf(r0) - 1.f;
    r1 = r1 > 0.f ? r1 : __expf(r1) - 1.f;
    r2 = r2 > 0.f ? r2 : __expf(r2) - 1.f;
    r3 = r3 > 0.f ? r3 : __expf(r3) - 1.f;
    r4 = r4 > 0.f ? r4 : __expf(r4) - 1.f;
    r5 = r5 > 0.f ? r5 : __expf(r5) - 1.f;
    r6 = r6 > 0.f ? r6 : __expf(r6) - 1.f;
    r7 = r7 > 0.f ? r7 : __expf(r7) - 1.f;
    uint4 p;
    p.x = pkbf(r0, r1);
    p.y = pkbf(r2, r3);
    p.z = pkbf(r4, r5);
    p.w = pkbf(r6, r7);
    *(uint4*)&xt[wid * 4 + g][4 * li] = p;
    __syncthreads();

    // ---- gemm2 phase: wave wid (<3) computes cols [wid*16, wid*16+16) ----
    if (wid < 3) {
        const int ci = wid;
        const int quad = g;               // lane>>4
        const int n = ci * 16 + li;
        floatx4 acc = {};
        #pragma unroll
        for (int ks = 0; ks < 4; ++ks) {
            const uint4 ax = *(const uint4*)&xt[li][ks * 16 + quad * 4];
            const bf16x8 a = *(const bf16x8*)&ax;
            const int gg = ks * 4 + quad;
            const uint4 bw = *(const uint4*)&w2g[n * 64 + ((gg ^ (n & 7)) << 2)];
            const bf16x8 b = *(const bf16x8*)&bw;
            acc = __builtin_amdgcn_mfma_f32_16x16x32_bf16(a, b, acc, 0, 0, 0);
        }
        #pragma unroll
        for (int r = 0; r < 4; ++r) {
            const int row = blockIdx.x * 16 + quad * 4 + r;
            const float v = acc[r];
            const float vn = __shfl_xor(v, 1, 64);
            if (ci < 2) {
                if (!(lane & 1))
                    h2b[(size_t)row * H2ROW + ci * 8 + (li >> 1)] = pkbf(v, vn);
            } else {
                if (!(lane & 1) && li < 8)
                    h2b[(size_t)row * H2ROW + 16 + (li >> 1)] = pkbf(v, vn);
                else if (li == 8)
                    h2b[(size_t)row * H2ROW + 20] = __float_as_uint(v);
                else if (li == 9)
                    er2[row] = v;
            }
        }
    }
}

// ================= layer-2 aggregation: 16-lane group per dst, colp prefetch =========
__global__ __launch_bounds__(256) void k_agg2(const int* __restrict__ cnt,
                                              const int* __restrict__ colp,
                                              const u32* __restrict__ h2b,
                                              const float* __restrict__ er2,
                                              const float* __restrict__ b2,
                                              float* __restrict__ out) {
    const int lane = threadIdx.x & 63, wid = threadIdx.x >> 6;
    const int g = lane >> 4, li = lane & 15;
    const int d = blockIdx.x * 16 + wid * 4 + g;      // grid sized exactly: d < NN
    const float erd = er2[d];
    const int beg = d << 6;
    const int end = beg + cnt[d];
    const u32 ob = (u32)(li < 12 ? 2 * li : 22) << 2;  // byte offset within 128B row

    float a0 = 0.f, a1 = 0.f, a2 = 0.f, a3 = 0.f;
    float ssum = 0.f;

    auto pres = [&](int e) -> int {
        const bool act = e < end;
        const int s = colp[act ? e : beg];
        return act ? s : 0;
    };

    auto bodyS = [&](int s, int e) {
        const bool act = e < end;
        const u32 rb = (u32)s << 7;                      // s*128 bytes
        const uint2 v = *(const uint2*)((const char*)h2b + (rb + ob));
        float c = __uint_as_float(*(const u32*)((const char*)h2b + rb + 80)) + erd;
        c = fmaxf(c, SLOPE * c);
        float w = __expf(c);
        w = act ? w : 0.f;
        ssum += w;
        a0 += w * bf_lo(v.x); a1 += w * bf_hi(v.x);
        a2 += w * bf_lo(v.y); a3 += w * bf_hi(v.y);
    };

    int e = beg;
    int4 cur;
    cur.x = pres(e);
    cur.y = pres(e + 1);
    cur.z = pres(e + 2);
    cur.w = pres(e + 3);
    while (__any(e < end)) {
        int4 nxt;
        nxt.x = pres(e + 4);
        nxt.y = pres(e + 5);
        nxt.z = pres(e + 6);
        nxt.w = pres(e + 7);
        bodyS(cur.x, e);
        bodyS(cur.y, e + 1);
        bodyS(cur.z, e + 2);
        bodyS(cur.w, e + 3);
        cur = nxt;
        e += 4;
    }

    if (li < 10) {
        const float inv = ssum > 0.f ? 1.f / ssum : 0.f;
        const float4 b = *(const float4*)&b2[4 * li];
        float4 r;
        r.x = a0 * inv + b.x;
        r.y = a1 * inv + b.y;
        r.z = a2 * inv + b.z;
        r.w = a3 * inv + b.w;
        *(float4*)&out[(size_t)d * C + 4 * li] = r;
    }
}

extern "C" void kernel_launch(void* const* d_in, const int* in_sizes, int n_in,
                              void* d_out, int out_size, void* d_ws, size_t ws_size,
                              hipStream_t stream) {
    const float* feat = (const float*)d_in[0];
    const int*   src  = (const int*)d_in[1];
    const int*   dst  = (const int*)d_in[2];
    const float* W1   = (const float*)d_in[3];
    const float* al1  = (const float*)d_in[4];
    const float* ar1  = (const float*)d_in[5];
    const float* b1   = (const float*)d_in[6];
    const float* W2   = (const float*)d_in[7];
    const float* al2  = (const float*)d_in[8];
    const float* ar2  = (const float*)d_in[9];
    const float* b2   = (const float*)d_in[10];
    float* out = (float*)d_out;

    // ---- workspace layout ----
    u32*   h1b = (u32*)d_ws;                        // N*64 u32 (bf16 h1 rows)
    u32*   xb2 = h1b + (size_t)NN * 64;             // N*64 u32: rank, then h2b (N*32)
    float* el1 = (float*)(xb2 + (size_t)NN * 64);   // N*4
    float* er1 = el1 + (size_t)NN * 4;              // N*4
    int* cnt   = (int*)(er1 + (size_t)NN * 4);      // N
    int* colp  = cnt + NN;                          // N*CAP padded buckets
    float* er2 = (float*)(colp + (size_t)NN * CAP); // N
    u32*   w2g = (u32*)(er2 + NN);                  // 48*64 u32 packed W2 tile
    int* rank  = (int*)xb2;                         // E ints, dead before agg1f writes h2b
    u32*   h2b = xb2;

    // ---- CSR build overlapped with GEMM1 (best-measured pairing: gemm1 ∥ hist) ----
    hipMemsetAsync(cnt, 0, (size_t)NN * sizeof(int), stream);
    k_g1h<<<FAT_BLOCKS, 256, 0, stream>>>(feat, W1, al1, ar1, h1b, el1, er1,
                                          dst, cnt, rank);
    k_bscat<<<HB_BLOCKS + 1, 256, 0, stream>>>(src, dst, rank, colp,
                                               W2, al2, ar2, w2g);

    // ---- layer 1 aggregation fused with GEMM2 ----
    k_agg1f<<<NN / 16, 256, 0, stream>>>(cnt, colp, h1b, el1, er1, b1,
                                         w2g, h2b, er2);

    // ---- layer 2 aggregation ----
    k_agg2<<<NN / 16, 256, 0, stream>>>(cnt, colp, h2b, er2, b2, out);
}

// Round 11
// 364.213 us; speedup vs baseline: 1.0774x; 1.0758x over previous
//
#include <hip/hip_runtime.h>
#include <math.h>

typedef unsigned int u32;
typedef __attribute__((ext_vector_type(8))) short bf16x8;
typedef __attribute__((ext_vector_type(4))) float floatx4;

constexpr int NN = 100000;
constexpr int EE = 1600000;
constexpr int IND = 256;
constexpr int F1 = 32;
constexpr int HF = 128;   // H*F1
constexpr int C  = 40;
constexpr float SLOPE = 0.2f;

constexpr int CAP = 64;   // padded bucket capacity per dst (P(deg>=64)~1e-13 at lambda=16)
constexpr int H2ROW = 32; // u32 per h2b row: 20 bf16x2 + el2 word + pad -> 128B line-aligned

constexpr int G1_BLOCKS  = (NN + 127) / 128;     // 782 gemm1 blocks
constexpr int HB_BLOCKS  = (EE / 4 + 255) / 256; // 1563 edge-quad blocks (4 edges/thread)
constexpr int FAT_BLOCKS = G1_BLOCKS + HB_BLOCKS;

__device__ __forceinline__ float bf_lo(u32 v) { return __uint_as_float(v << 16); }
__device__ __forceinline__ float bf_hi(u32 v) { return __uint_as_float(v & 0xffff0000u); }

// hardware packed f32->bf16 (RNE), 1 inst instead of ~11; lo -> low half
__device__ __forceinline__ u32 pkbf(float lo, float hi) {
    u32 r;
    asm("v_cvt_pk_bf16_f32 %0, %1, %2" : "=v"(r) : "v"(lo), "v"(hi));
    return r;
}

// ============ FAT kernel: gemm1 blocks interleaved with hist blocks (best pairing) =====
// blockIdx%3==0 -> gemm1 (782 blocks, 64KB W1 stage — measured faster than 32KB 2-pass),
// else hist (1563 blocks, 4 independent returning atomics/thread -> rank).
__global__ __launch_bounds__(256) void k_g1h(const float* __restrict__ feat,
                                             const float* __restrict__ W1,
                                             const float* __restrict__ al1,
                                             const float* __restrict__ ar1,
                                             u32* __restrict__ h1b,
                                             float* __restrict__ el1,
                                             float* __restrict__ er1,
                                             const int* __restrict__ dst,
                                             int* __restrict__ cnt,
                                             int* __restrict__ rank) {
    __shared__ u32 w1t[128 * 128];
    const int bx = blockIdx.x;
    const int tid = threadIdx.x;

    if (bx % 3 != 0) {
        // ---------------- hist role ----------------
        const int hb = bx - bx / 3 - 1;
        const int e = (hb * 256 + tid) * 4;
        if (e < EE) {   // EE % 4 == 0
            const int4 d4 = *(const int4*)&dst[e];
            int4 r4;
            r4.x = atomicAdd(&cnt[d4.x], 1);
            r4.y = atomicAdd(&cnt[d4.y], 1);
            r4.z = atomicAdd(&cnt[d4.z], 1);
            r4.w = atomicAdd(&cnt[d4.w], 1);
            *(int4*)&rank[e] = r4;
        }
        return;
    }

    // ---------------- gemm1 role ----------------
    const int bid = bx / 3;
    {
        const int n = tid & 127;
        const int o0 = (tid >> 7) * 16;
        for (int i = 0; i < 16; ++i) {
            const int o = o0 + i;
            float f0 = W1[(size_t)(o * 8 + 0) * HF + n];
            float f1 = W1[(size_t)(o * 8 + 1) * HF + n];
            float f2 = W1[(size_t)(o * 8 + 2) * HF + n];
            float f3 = W1[(size_t)(o * 8 + 3) * HF + n];
            float f4 = W1[(size_t)(o * 8 + 4) * HF + n];
            float f5 = W1[(size_t)(o * 8 + 5) * HF + n];
            float f6 = W1[(size_t)(o * 8 + 6) * HF + n];
            float f7 = W1[(size_t)(o * 8 + 7) * HF + n];
            uint4 p;
            p.x = pkbf(f0, f1);
            p.y = pkbf(f2, f3);
            p.z = pkbf(f4, f5);
            p.w = pkbf(f6, f7);
            *(uint4*)&w1t[n * 128 + ((o ^ (n & 7)) << 2)] = p;
        }
    }
    __syncthreads();

    const int w = tid >> 6, lane = tid & 63;
    const int quad = lane >> 4, l15 = lane & 15;
    const int rbase = bid * 128 + w * 32;

    float alv[4][2], arv[4][2];
    #pragma unroll
    for (int h = 0; h < 4; ++h) {
        alv[h][0] = al1[h * F1 + l15];
        alv[h][1] = al1[h * F1 + 16 + l15];
        arv[h][0] = ar1[h * F1 + l15];
        arv[h][1] = ar1[h * F1 + 16 + l15];
    }

    floatx4 acc[2][8] = {};
    for (int ks = 0; ks < 8; ++ks) {
        bf16x8 a[2];
        #pragma unroll
        for (int ri = 0; ri < 2; ++ri) {
            int row = rbase + ri * 16 + l15;
            row = row < NN ? row : NN - 1;
            const size_t base = (size_t)row * IND + ks * 32 + quad * 8;
            const float4 f0 = *(const float4*)&feat[base];
            const float4 f1 = *(const float4*)&feat[base + 4];
            uint4 p;
            p.x = pkbf(f0.x, f0.y);
            p.y = pkbf(f0.z, f0.w);
            p.z = pkbf(f1.x, f1.y);
            p.w = pkbf(f1.z, f1.w);
            a[ri] = *(bf16x8*)&p;
        }
        const int g = ks * 4 + quad;
        #pragma unroll
        for (int ci = 0; ci < 8; ++ci) {
            const int n = ci * 16 + l15;
            uint4 bw = *(const uint4*)&w1t[n * 128 + ((g ^ (n & 7)) << 2)];
            bf16x8 b = *(bf16x8*)&bw;
            acc[0][ci] = __builtin_amdgcn_mfma_f32_16x16x32_bf16(a[0], b, acc[0][ci], 0, 0, 0);
            acc[1][ci] = __builtin_amdgcn_mfma_f32_16x16x32_bf16(a[1], b, acc[1][ci], 0, 0, 0);
        }
    }

    #pragma unroll
    for (int ri = 0; ri < 2; ++ri) {
        #pragma unroll
        for (int r = 0; r < 4; ++r) {
            const int row = rbase + ri * 16 + quad * 4 + r;
            const bool rok = row < NN;
            #pragma unroll
            for (int h = 0; h < 4; ++h) {
                float pe = acc[ri][2 * h][r] * alv[h][0] + acc[ri][2 * h + 1][r] * alv[h][1];
                float pr = acc[ri][2 * h][r] * arv[h][0] + acc[ri][2 * h + 1][r] * arv[h][1];
                #pragma unroll
                for (int m = 1; m < 16; m <<= 1) {
                    pe += __shfl_xor(pe, m, 64);
                    pr += __shfl_xor(pr, m, 64);
                }
                if (l15 == 0 && rok) {
                    el1[row * 4 + h] = pe;
                    er1[row * 4 + h] = pr;
                }
            }
            #pragma unroll
            for (int ci = 0; ci < 8; ++ci) {
                float v = acc[ri][ci][r];
                float vn = __shfl_xor(v, 1, 64);
                if (!(lane & 1) && rok) {
                    h1b[(size_t)row * 64 + ci * 8 + (l15 >> 1)] = pkbf(v, vn);
                }
            }
        }
    }
}

// ============ bucket scatter + W2 pack role ==========
// blocks 0..HB_BLOCKS-1: atomic-free scatter p=(dst<<6)+rank, 4 edges/thread.
// block HB_BLOCKS: pack W2 (+ aux cols 40=W2@al2, 41=W2@ar2) into w2g.
__global__ __launch_bounds__(256) void k_bscat(const int* __restrict__ src,
                                               const int* __restrict__ dst,
                                               const int* __restrict__ rank,
                                               int* __restrict__ colp,
                                               const float* __restrict__ W2,
                                               const float* __restrict__ al2,
                                               const float* __restrict__ ar2,
                                               u32* __restrict__ w2g) {
    const int tid = threadIdx.x;
    if (blockIdx.x == HB_BLOCKS) {
        const int o = tid & 15;
        const int n0 = tid >> 4;
        for (int n = n0; n < 48; n += 16) {
            float f[8];
            #pragma unroll
            for (int j = 0; j < 8; ++j) {
                const int k = o * 8 + j;
                float v;
                if (n < C) v = W2[(size_t)k * C + n];
                else if (n == 40) {
                    v = 0.f;
                    for (int c = 0; c < C; ++c) v += W2[(size_t)k * C + c] * al2[c];
                } else if (n == 41) {
                    v = 0.f;
                    for (int c = 0; c < C; ++c) v += W2[(size_t)k * C + c] * ar2[c];
                } else v = 0.f;
                f[j] = v;
            }
            uint4 p;
            p.x = pkbf(f[0], f[1]);
            p.y = pkbf(f[2], f[3]);
            p.z = pkbf(f[4], f[5]);
            p.w = pkbf(f[6], f[7]);
            *(uint4*)&w2g[n * 64 + ((o ^ (n & 7)) << 2)] = p;
        }
        return;
    }
    const int e = (blockIdx.x * 256 + tid) * 4;
    if (e < EE) {   // EE % 4 == 0
        const int4 d4 = *(const int4*)&dst[e];
        const int4 s4 = *(const int4*)&src[e];
        const int4 r4 = *(const int4*)&rank[e];
        colp[(d4.x << 6) + r4.x] = s4.x;
        colp[(d4.y << 6) + r4.y] = s4.y;
        colp[(d4.z << 6) + r4.z] = s4.z;
        colp[(d4.w << 6) + r4.w] = s4.w;
    }
}

// ========== fused layer-1 aggregation + GEMM2: 16 dsts/block == one 16-row tile ======
// Phase 1 (agg): 16-lane group per dst, 4-deep edge ILP (no prefetch — measured best),
// ELU -> bf16 row into LDS xt.
// Phase 2 (gemm2): waves 0..2 each compute one 16-col slab of x @ [W2|aux] (4 MFMAs)
// and write h2b (separate buffer from h1b -> no aliasing race) + el2/er2.
__global__ __launch_bounds__(256) void k_agg1f(const int* __restrict__ cnt,
                                               const int* __restrict__ colp,
                                               const u32* __restrict__ h1b,
                                               const float* __restrict__ el1,
                                               const float* __restrict__ er1,
                                               const float* __restrict__ b1,
                                               const u32* __restrict__ w2g,
                                               u32* __restrict__ h2b,
                                               float* __restrict__ er2) {
    __shared__ u32 xt[16][68];   // 16 rows x 64 u32 (+4 pad: 2-way max bank aliasing)
    const int lane = threadIdx.x & 63, wid = threadIdx.x >> 6;
    const int g = lane >> 4, li = lane & 15;
    const int d = blockIdx.x * 16 + wid * 4 + g;      // grid sized exactly: d < NN
    const int head = li >> 2;
    const float erd = er1[d * 4 + head];
    const int beg = d << 6;
    const int end = beg + cnt[d];
    const u32 li16 = (u32)li << 4;
    const u32 hoff = (u32)head << 2;

    float a0 = 0.f, a1 = 0.f, a2 = 0.f, a3 = 0.f;
    float a4 = 0.f, a5 = 0.f, a6 = 0.f, a7 = 0.f;
    float ssum = 0.f;

    auto body = [&](int e) {
        const bool act = e < end;
        int s = colp[act ? e : beg];   // bucket slots always in-bounds of colp
        s = act ? s : 0;               // pad slots may be uninitialized
        const u32 rb = (u32)s << 8;
        const uint4 v = *(const uint4*)((const char*)h1b + (rb + li16));
        float c = *(const float*)((const char*)el1 + (((u32)s << 4) + hoff)) + erd;
        c = fmaxf(c, SLOPE * c);
        float w = __expf(c);
        w = act ? w : 0.f;
        ssum += w;
        a0 += w * bf_lo(v.x); a1 += w * bf_hi(v.x);
        a2 += w * bf_lo(v.y); a3 += w * bf_hi(v.y);
        a4 += w * bf_lo(v.z); a5 += w * bf_hi(v.z);
        a6 += w * bf_lo(v.w); a7 += w * bf_hi(v.w);
    };

    int e = beg;
    while (__any(e < end)) {
        body(e);
        body(e + 1);
        body(e + 2);
        body(e + 3);
        e += 4;
    }

    const float inv = ssum > 0.f ? 1.f / ssum : 0.f;
    const float4 ba = *(const float4*)&b1[8 * li];
    const float4 bb = *(const float4*)&b1[8 * li + 4];
    float r0 = a0 * inv + ba.x, r1 = a1 * inv + ba.y;
    float r2 = a2 * inv + ba.z, r3 = a3 * inv + ba.w;
    float r4 = a4 * inv + bb.x, r5 = a5 * inv + bb.y;
    float r6 = a6 * inv + bb.z, r7 = a7 * inv + bb.w;
    r0 = r0 > 0.f ? r0 : __expf(r0) - 1.f;
    r1 = r1 > 0.f ? r1 : __expf(r1) - 1.f;
    r2 = r2 > 0.f ? r2 : __expf(r2) - 1.f;
    r3 = r3 > 0.f ? r3 : __expf(r3) - 1.f;
    r4 = r4 > 0.f ? r4 : __expf(r4) - 1.f;
    r5 = r5 > 0.f ? r5 : __expf(r5) - 1.f;
    r6 = r6 > 0.f ? r6 : __expf(r6) - 1.f;
    r7 = r7 > 0.f ? r7 : __expf(r7) - 1.f;
    uint4 p;
    p.x = pkbf(r0, r1);
    p.y = pkbf(r2, r3);
    p.z = pkbf(r4, r5);
    p.w = pkbf(r6, r7);
    *(uint4*)&xt[wid * 4 + g][4 * li] = p;
    __syncthreads();

    // ---- gemm2 phase: wave wid (<3) computes cols [wid*16, wid*16+16) ----
    if (wid < 3) {
        const int ci = wid;
        const int quad = g;               // lane>>4
        const int n = ci * 16 + li;
        floatx4 acc = {};
        #pragma unroll
        for (int ks = 0; ks < 4; ++ks) {
            const uint4 ax = *(const uint4*)&xt[li][ks * 16 + quad * 4];
            const bf16x8 a = *(const bf16x8*)&ax;
            const int gg = ks * 4 + quad;
            const uint4 bw = *(const uint4*)&w2g[n * 64 + ((gg ^ (n & 7)) << 2)];
            const bf16x8 b = *(const bf16x8*)&bw;
            acc = __builtin_amdgcn_mfma_f32_16x16x32_bf16(a, b, acc, 0, 0, 0);
        }
        #pragma unroll
        for (int r = 0; r < 4; ++r) {
            const int row = blockIdx.x * 16 + quad * 4 + r;
            const float v = acc[r];
            const float vn = __shfl_xor(v, 1, 64);
            if (ci < 2) {
                if (!(lane & 1))
                    h2b[(size_t)row * H2ROW + ci * 8 + (li >> 1)] = pkbf(v, vn);
            } else {
                if (!(lane & 1) && li < 8)
                    h2b[(size_t)row * H2ROW + 16 + (li >> 1)] = pkbf(v, vn);
                else if (li == 8)
                    h2b[(size_t)row * H2ROW + 20] = __float_as_uint(v);
                else if (li == 9)
                    er2[row] = v;
            }
        }
    }
}

// ================= layer-2 aggregation: 16-lane group per dst, 4-deep edge ILP =======
__global__ __launch_bounds__(256) void k_agg2(const int* __restrict__ cnt,
                                              const int* __restrict__ colp,
                                              const u32* __restrict__ h2b,
                                              const float* __restrict__ er2,
                                              const float* __restrict__ b2,
                                              float* __restrict__ out) {
    const int lane = threadIdx.x & 63, wid = threadIdx.x >> 6;
    const int g = lane >> 4, li = lane & 15;
    const int d = blockIdx.x * 16 + wid * 4 + g;      // grid sized exactly: d < NN
    const float erd = er2[d];
    const int beg = d << 6;
    const int end = beg + cnt[d];
    const u32 ob = (u32)(li < 12 ? 2 * li : 22) << 2;  // byte offset within 128B row

    float a0 = 0.f, a1 = 0.f, a2 = 0.f, a3 = 0.f;
    float ssum = 0.f;

    auto body = [&](int e) {
        const bool act = e < end;
        int s = colp[act ? e : beg];
        s = act ? s : 0;
        const u32 rb = (u32)s << 7;                      // s*128 bytes
        const uint2 v = *(const uint2*)((const char*)h2b + (rb + ob));
        float c = __uint_as_float(*(const u32*)((const char*)h2b + rb + 80)) + erd;
        c = fmaxf(c, SLOPE * c);
        float w = __expf(c);
        w = act ? w : 0.f;
        ssum += w;
        a0 += w * bf_lo(v.x); a1 += w * bf_hi(v.x);
        a2 += w * bf_lo(v.y); a3 += w * bf_hi(v.y);
    };

    int e = beg;
    while (__any(e < end)) {
        body(e);
        body(e + 1);
        body(e + 2);
        body(e + 3);
        e += 4;
    }

    if (li < 10) {
        const float inv = ssum > 0.f ? 1.f / ssum : 0.f;
        const float4 b = *(const float4*)&b2[4 * li];
        float4 r;
        r.x = a0 * inv + b.x;
        r.y = a1 * inv + b.y;
        r.z = a2 * inv + b.z;
        r.w = a3 * inv + b.w;
        *(float4*)&out[(size_t)d * C + 4 * li] = r;
    }
}

extern "C" void kernel_launch(void* const* d_in, const int* in_sizes, int n_in,
                              void* d_out, int out_size, void* d_ws, size_t ws_size,
                              hipStream_t stream) {
    const float* feat = (const float*)d_in[0];
    const int*   src  = (const int*)d_in[1];
    const int*   dst  = (const int*)d_in[2];
    const float* W1   = (const float*)d_in[3];
    const float* al1  = (const float*)d_in[4];
    const float* ar1  = (const float*)d_in[5];
    const float* b1   = (const float*)d_in[6];
    const float* W2   = (const float*)d_in[7];
    const float* al2  = (const float*)d_in[8];
    const float* ar2  = (const float*)d_in[9];
    const float* b2   = (const float*)d_in[10];
    float* out = (float*)d_out;

    // ---- workspace layout ----
    u32*   h1b = (u32*)d_ws;                        // N*64 u32 (bf16 h1 rows)
    u32*   xb2 = h1b + (size_t)NN * 64;             // N*64 u32: rank, then h2b (N*32)
    float* el1 = (float*)(xb2 + (size_t)NN * 64);   // N*4
    float* er1 = el1 + (size_t)NN * 4;              // N*4
    int* cnt   = (int*)(er1 + (size_t)NN * 4);      // N
    int* colp  = cnt + NN;                          // N*CAP padded buckets
    float* er2 = (float*)(colp + (size_t)NN * CAP); // N
    u32*   w2g = (u32*)(er2 + NN);                  // 48*64 u32 packed W2 tile
    int* rank  = (int*)xb2;                         // E ints, dead before agg1f writes h2b
    u32*   h2b = xb2;

    // ---- CSR build overlapped with GEMM1 (best-measured pairing: gemm1 ∥ hist) ----
    hipMemsetAsync(cnt, 0, (size_t)NN * sizeof(int), stream);
    k_g1h<<<FAT_BLOCKS, 256, 0, stream>>>(feat, W1, al1, ar1, h1b, el1, er1,
                                          dst, cnt, rank);
    k_bscat<<<HB_BLOCKS + 1, 256, 0, stream>>>(src, dst, rank, colp,
                                               W2, al2, ar2, w2g);

    // ---- layer 1 aggregation fused with GEMM2 ----
    k_agg1f<<<NN / 16, 256, 0, stream>>>(cnt, colp, h1b, el1, er1, b1,
                                         w2g, h2b, er2);

    // ---- layer 2 aggregation ----
    k_agg2<<<NN / 16, 256, 0, stream>>>(cnt, colp, h2b, er2, b2, out);
}